// Round 6
// baseline (371.131 us; speedup 1.0000x reference)
//
#include <hip/hip_runtime.h>
#include <math.h>

// CPQuadRankLayer: B=16, N=2048, IN=OUT=256, R=64, Q=4.
// out[b,n,o] = sum_r ( prod_q rmsnorm_r(x[b,n,q,:] @ Fq[n]^T) )[r] * gain[n] * Fo[n,r,o]
//              + mean_q x[b,n,q,o]
//
// R5: 200us, zero spill, 2 WG/CU. Pipe budget showed VALU+LDS+HBM nearly
// additive (sum ~= dur): serialization at per-n WG boundaries, the tail
// vmcnt(0)+x-reread, and 128 broadcast ds_read_b32 m-reads.
// R6: persistent WGs (grid 512, ITERS=4 consecutive n each) with next-n
// slab/x prefetch woven into the fo epilogue (pipeline never drains at n
// boundaries); residual x loads hoisted to just after the phase loop (latency
// hidden under reduce/RMS/merge; FO waits recounted 12/12/10/0); out-GEMM m
// values via 2 ds_read + v_readlane instead of 128 broadcast ds_read_b32.
//
// Factor stream per n: 20 x 16KB slabs (16 proj i16-slices + 4 fo quarters)
// through a 3-slot LDS ring via global_load_lds(16B); x as 4KB i16 chunks in
// a 2-slot buffer. Counted vmcnt (never 0 mid-stream), raw s_barrier.

#define WAITVM(NLIT) asm volatile("s_waitcnt vmcnt(" #NLIT ") lgkmcnt(0)" ::: "memory")
#define LGKM0()      asm volatile("s_waitcnt lgkmcnt(0)" ::: "memory")
#define BARRIER()    __builtin_amdgcn_s_barrier()
#define MEMFENCE()   asm volatile("" ::: "memory")

__device__ __forceinline__ void g2l16(const float* g, float* l) {
  __builtin_amdgcn_global_load_lds(
      (const __attribute__((address_space(1))) void*)g,
      (__attribute__((address_space(3))) void*)l, 16, 0, 0);
}

#define NN 2048
#define ITERS 4

__global__ __launch_bounds__(512, 2) void cpquad_kernel(
    const float* __restrict__ x,
    const float* __restrict__ ftl, const float* __restrict__ ftr,
    const float* __restrict__ fbl, const float* __restrict__ fbr,
    const float* __restrict__ fout, const float* __restrict__ gain,
    float* __restrict__ out) {

  // LDS: 12288 + 2048 + 4096 + 64 floats = 72.25 KB -> 2 WG/CU
  alignas(16) __shared__ float s_fb[3 * 4096]; // ring: proj slab [4q][64r][16i] / fo quarter [16r][256o]
  alignas(16) __shared__ float s_xs[2 * 1024]; // x i16 chunk dbuf: [64 c2=b*4+q][16 i]
  alignas(16) __shared__ float s_ps[4096];     // [4 q][16 b][64 r]; plane0 overwritten by merged
  __shared__ float s_rr[64];                   // [4 q][16 b] 1/rms

  const int t = threadIdx.x, lane = t & 63, wid = t >> 6;
  const int n0 = blockIdx.x * ITERS;

  // ---------- per-WG-constant staging geometry ----------
  // proj slab: wave w stages quadrant q=w>>1, rows r0=(w&1)*32+(lane>>2) and
  // r0+16. Source 16B slot XOR-swizzled by (r>>1)&3 = (lane>>3)&3 (LDS dest
  // linear as global_load_lds requires; swizzle on the global source only —
  // both-sides-or-neither rule, read side uses fsl below).
  const int q0 = wid >> 1;
  const int r0 = (wid & 1) * 32 + (lane >> 2);
  const float* fq0 = (q0 == 0) ? ftl : ((q0 == 1) ? ftr : ((q0 == 2) ? fbl : fbr));
  const float* ss0 =
      fq0 + ((size_t)n0 * 64 + r0) * 256 + (((lane & 3) ^ ((lane >> 3) & 3)) << 2);
  // x chunk (waves 0-3 only, 1KB/phase): c2 = wid*16 + (lane>>2)
  const int c2 = wid * 16 + (lane >> 2);
  const float* xsrc =
      x + (((size_t)(c2 >> 2) * NN + n0) * 4 + (c2 & 3)) * 256 + (lane & 3) * 4;
  // fo quarter: linear [16r][256o]
  const float* osrc = fout + (size_t)n0 * 16384 + wid * 512 + lane * 4;

  auto ISSUE_SLAB = [&](int s) {
    float* d = s_fb + (s % 3) * 4096 + wid * 512;
    g2l16(ss0 + s * 16, d);              // rows r0
    g2l16(ss0 + 4096 + s * 16, d + 256); // rows r0+16
  };
  auto ISSUE_X = [&](int p) {
    if (wid < 4) g2l16(xsrc + p * 16, s_xs + (p & 1) * 1024 + wid * 256);
  };
  auto ISSUE_FO = [&](int h) {
    float* d = s_fb + ((16 + h) % 3) * 4096 + wid * 512;
    g2l16(osrc + h * 4096, d);
    g2l16(osrc + h * 4096 + 256, d + 256);
  };

  // compute decomposition: iseg 4i, bh b-half, rg base-r (rows rg+{0,16,32,48}), qq quadrant
  const int iseg = t & 3;
  const int bh   = (t >> 2) & 1;
  const int rg   = (t >> 3) & 15;
  const int qq   = t >> 7;
  const int fsl  = (iseg ^ ((rg >> 1) & 3)) << 2; // swizzled fv slot (floats)

#pragma unroll 1
  for (int it = 0; it < ITERS; ++it) {
    const int n = n0 + it;
    const float gn = gain[n]; // in-queue position analyzed: retired by p<=1's counted wait

    if (it == 0) { // later iters: prefetched by previous epilogue
      ISSUE_X(0);
      ISSUE_SLAB(0);
      ISSUE_SLAB(1);
    }

    float acc[4][8];
#pragma unroll
    for (int k = 0; k < 4; ++k)
#pragma unroll
      for (int b = 0; b < 8; ++b) acc[k][b] = 0.0f;

    // ---------- 16 projection phases (i16 slices) ----------
    // unroll 2 only: full unroll hoists addresses -> spill (R4 lesson).
#pragma unroll 2
    for (int p = 0; p < 16; ++p) {
      if (p < 15) ISSUE_X(p + 1);
      if (p < 14) ISSUE_SLAB(p + 2); else ISSUE_FO(p - 14);
      // each phase's wait retires exactly its slab (+x); stores/gain from the
      // previous iteration sit ahead in-queue and retire harmlessly earlier.
      if (p < 15) {
        if (wid < 4) { WAITVM(5); } else { WAITVM(4); }
      } else {
        WAITVM(4);
      }
      BARRIER();

      const float* fb = s_fb + (p % 3) * 4096 + qq * 1024;
      const float* xb = s_xs + (p & 1) * 1024;
      float4 fv[4];
#pragma unroll
      for (int k = 0; k < 4; ++k)
        fv[k] = *(const float4*)(fb + (k * 16 + rg) * 16 + fsl);
#pragma unroll
      for (int h2 = 0; h2 < 2; ++h2) {
        float4 xv[4];
#pragma unroll
        for (int bb = 0; bb < 4; ++bb)
          xv[bb] = *(const float4*)(xb + ((bh * 8 + h2 * 4 + bb) * 4 + qq) * 16 + (iseg << 2));
#pragma unroll
        for (int k = 0; k < 4; ++k)
#pragma unroll
          for (int bb = 0; bb < 4; ++bb) {
            acc[k][h2 * 4 + bb] = fmaf(fv[k].x, xv[bb].x, acc[k][h2 * 4 + bb]);
            acc[k][h2 * 4 + bb] = fmaf(fv[k].y, xv[bb].y, acc[k][h2 * 4 + bb]);
            acc[k][h2 * 4 + bb] = fmaf(fv[k].z, xv[bb].z, acc[k][h2 * 4 + bb]);
            acc[k][h2 * 4 + bb] = fmaf(fv[k].w, xv[bb].w, acc[k][h2 * 4 + bb]);
          }
      }
      LGKM0();
      BARRIER(); // buffer-reuse fence
    }

    // queue now: [FO0(2), FO1(2)] (p15 left vmcnt=4)
    ISSUE_FO(2);
    MEMFENCE(); // pin xr AFTER FO2 in the vmem queue (counts below depend on order)
    // ---------- hoisted residual x loads (latency hides under reduce/RMS) ----
    float4 xr0[4], xr1[4];
#pragma unroll
    for (int q = 0; q < 4; ++q) {
      xr0[q] = *(const float4*)(x + (((size_t)(wid * 2 + 0) * NN + n) * 4 + q) * 256 + (lane << 2));
      xr1[q] = *(const float4*)(x + (((size_t)(wid * 2 + 1) * NN + n) * 4 + q) * 256 + (lane << 2));
    }
    MEMFENCE();
    // queue: [FO0(2), FO1(2), FO2(2), xr(8)] = 14

    // ---------- reduce over iseg, write P ----------
#pragma unroll
    for (int k = 0; k < 4; ++k)
#pragma unroll
      for (int b = 0; b < 8; ++b) {
        float v = acc[k][b];
        v += __shfl_xor(v, 1);
        v += __shfl_xor(v, 2);
        acc[k][b] = v;
      }
#pragma unroll
    for (int k = 0; k < 4; ++k) {
      if (iseg == k) { // static acc index
#pragma unroll
        for (int b = 0; b < 8; ++b)
          s_ps[qq * 1024 + (bh * 8 + b) * 64 + k * 16 + rg] = acc[k][b];
      }
    }
    LGKM0(); BARRIER();

    // ---------- RMS per (q,b) row ----------
#pragma unroll
    for (int j = 0; j < 8; ++j) {
      const int row = wid * 8 + j;
      const float v = s_ps[row * 64 + lane];
      float ssum = v * v;
#pragma unroll
      for (int d = 1; d < 64; d <<= 1) ssum += __shfl_xor(ssum, d);
      if (lane == 0) s_rr[row] = 1.0f / sqrtf(ssum * (1.0f / 64.0f) + 1e-6f);
    }
    LGKM0(); BARRIER();

    // ---------- merged[b][r] -> s_ps plane 0 (element-owned, race-free) ------
#pragma unroll
    for (int e0 = 0; e0 < 2; ++e0) {
      const int e = t + e0 * 512;
      const int b = e >> 6, r = e & 63;
      float m = gn;
#pragma unroll
      for (int q = 0; q < 4; ++q) m *= s_ps[q * 1024 + b * 64 + r] * s_rr[q * 16 + b];
      s_ps[b * 64 + r] = m;
    }

    // ---------- out GEMM over 4 fo quarters: thread = (2 b) x (4 o) ----------
    // need FO0 (slot1): queue [FO0 2, FO1 2, FO2 2, xr 8] -> N=12
    WAITVM(12); BARRIER(); // + merged visibility
    // per-lane merged rows; m(b, r) = readlane(mv_b, r) — off the LDS pipe
    const float mv0 = s_ps[(wid * 2 + 0) * 64 + lane];
    const float mv1 = s_ps[(wid * 2 + 1) * 64 + lane];

    float oa[2][4] = {{0.f, 0.f, 0.f, 0.f}, {0.f, 0.f, 0.f, 0.f}};
    auto gemq = [&](int h, const float* fsp) {
#pragma unroll
      for (int rr = 0; rr < 16; ++rr) {
        const float4 f4 = *(const float4*)(fsp + rr * 256 + (lane << 2));
        const float m0 = __uint_as_float(__builtin_amdgcn_readlane(__float_as_uint(mv0), h * 16 + rr));
        const float m1 = __uint_as_float(__builtin_amdgcn_readlane(__float_as_uint(mv1), h * 16 + rr));
        oa[0][0] = fmaf(m0, f4.x, oa[0][0]); oa[0][1] = fmaf(m0, f4.y, oa[0][1]);
        oa[0][2] = fmaf(m0, f4.z, oa[0][2]); oa[0][3] = fmaf(m0, f4.w, oa[0][3]);
        oa[1][0] = fmaf(m1, f4.x, oa[1][0]); oa[1][1] = fmaf(m1, f4.y, oa[1][1]);
        oa[1][2] = fmaf(m1, f4.z, oa[1][2]); oa[1][3] = fmaf(m1, f4.w, oa[1][3]);
      }
    };

    gemq(0, s_fb + 1 * 4096);            // FO0
    BARRIER();                           // slot1 readers done
    ISSUE_FO(3);                         // FO3 -> slot1
    // need FO1 (slot2): queue [FO1 2, FO2 2, xr 8, FO3 2] -> N=12
    WAITVM(12); BARRIER();
    gemq(1, s_fb + 2 * 4096);            // FO1
    // need FO2 (slot0): queue [FO2 2, xr 8, FO3 2] -> N=10
    WAITVM(10); BARRIER();
    gemq(2, s_fb + 0 * 4096);            // FO2
    // need FO3 (slot1): nothing after it in queue -> full drain (once per n)
    WAITVM(0); BARRIER();                // all waves also past h2 -> slot0 free
    if (it != ITERS - 1) {
      // advance to n+1 and start its prologue NOW (slot0 + x buf0 are free;
      // slot1 is being read by gemq(3) below, its slab goes after the barrier)
      ss0 += 16384; xsrc += 1024; osrc += 16384;
      ISSUE_X(0);
      ISSUE_SLAB(0);
    }
    gemq(3, s_fb + 1 * 4096);            // FO3
    BARRIER();                           // slot1 readers done
    if (it != ITERS - 1) ISSUE_SLAB(1);  // -> slot1
    // queue now (non-last): [X0'(w<4), S0'(2), S1'(2)] — exactly the prologue
    // pattern the phase-0 counted wait expects.

    // ---------- store: out[b][n][o] = gemm + 0.25*sum_q x ----------
    {
      const int b0 = wid * 2;
      float4 o4;
      o4.x = oa[0][0] + 0.25f * (xr0[0].x + xr0[1].x + xr0[2].x + xr0[3].x);
      o4.y = oa[0][1] + 0.25f * (xr0[0].y + xr0[1].y + xr0[2].y + xr0[3].y);
      o4.z = oa[0][2] + 0.25f * (xr0[0].z + xr0[1].z + xr0[2].z + xr0[3].z);
      o4.w = oa[0][3] + 0.25f * (xr0[0].w + xr0[1].w + xr0[2].w + xr0[3].w);
      *(float4*)(out + ((size_t)b0 * NN + n) * 256 + (lane << 2)) = o4;
      o4.x = oa[1][0] + 0.25f * (xr1[0].x + xr1[1].x + xr1[2].x + xr1[3].x);
      o4.y = oa[1][1] + 0.25f * (xr1[0].y + xr1[1].y + xr1[2].y + xr1[3].y);
      o4.z = oa[1][2] + 0.25f * (xr1[0].z + xr1[1].z + xr1[2].z + xr1[3].z);
      o4.w = oa[1][3] + 0.25f * (xr1[0].w + xr1[1].w + xr1[2].w + xr1[3].w);
      *(float4*)(out + ((size_t)(b0 + 1) * NN + n) * 256 + (lane << 2)) = o4;
    }
  }
}

extern "C" void kernel_launch(void* const* d_in, const int* in_sizes, int n_in,
                              void* d_out, int out_size, void* d_ws, size_t ws_size,
                              hipStream_t stream) {
  const float* x   = (const float*)d_in[0];
  const float* ftl = (const float*)d_in[1];
  const float* ftr = (const float*)d_in[2];
  const float* fbl = (const float*)d_in[3];
  const float* fbr = (const float*)d_in[4];
  const float* fo  = (const float*)d_in[5];
  const float* gn  = (const float*)d_in[6];
  float* o = (float*)d_out;
  cpquad_kernel<<<dim3(NN / ITERS), dim3(512), 0, stream>>>(x, ftl, ftr, fbl, fbr, fo, gn, o);
}

// Round 7
// 349.949 us; speedup vs baseline: 1.0605x; 1.0605x over previous
//
#include <hip/hip_runtime.h>
#include <math.h>

// CPQuadRankLayer: B=16, N=2048, IN=OUT=256, R=64, Q=4.
// out[b,n,o] = sum_r ( prod_q rmsnorm_r(x[b,n,q,:] @ Fq[n]^T) )[r] * gain[n] * Fo[n,r,o]
//              + mean_q x[b,n,q,o]
//
// R5: 200us @ 64 VGPR, zero spill, 2 WG/CU. R6 (persistent + hoisted residual
// + readlane) regressed to 371us: hoisted xr[32 regs] spanned the epilogue ->
// 128-cap spill (WRITE 274MB). R7 = R6 minus the hoist: persistent WGs
// (ITERS=4, grid 512 = exactly 2 resident WG/CU, one generation, no boundary
// drains) + readlane m-values (+2 regs), residual re-read back at the tail
// where R5 measured spill-free.
//
// Factor stream per n: 20 x 16KB slabs (16 proj i16-slices + 4 fo quarters)
// through a 3-slot LDS ring via global_load_lds(16B); x as 4KB i16 chunks in
// a 2-slot buffer. Counted vmcnt (never 0 mid-stream), raw s_barrier.
// Next-n prologue (X0,S0,S1) is issued inside the fo epilogue; queue algebra:
// entering next p0, queue=[X0',S0',S1',st2] so WAITVM(5)/(4) retires exactly
// X0'+S0'+S1' and steady state resumes by p2 (all waits strict-safe).

#define WAITVM(NLIT) asm volatile("s_waitcnt vmcnt(" #NLIT ") lgkmcnt(0)" ::: "memory")
#define LGKM0()      asm volatile("s_waitcnt lgkmcnt(0)" ::: "memory")
#define BARRIER()    __builtin_amdgcn_s_barrier()

__device__ __forceinline__ void g2l16(const float* g, float* l) {
  __builtin_amdgcn_global_load_lds(
      (const __attribute__((address_space(1))) void*)g,
      (__attribute__((address_space(3))) void*)l, 16, 0, 0);
}

#define NN 2048
#define ITERS 4

__global__ __launch_bounds__(512, 2) void cpquad_kernel(
    const float* __restrict__ x,
    const float* __restrict__ ftl, const float* __restrict__ ftr,
    const float* __restrict__ fbl, const float* __restrict__ fbr,
    const float* __restrict__ fout, const float* __restrict__ gain,
    float* __restrict__ out) {

  // LDS: 12288 + 2048 + 4096 + 64 floats = 72.25 KB -> 2 WG/CU
  alignas(16) __shared__ float s_fb[3 * 4096]; // ring: proj slab [4q][64r][16i] / fo quarter [16r][256o]
  alignas(16) __shared__ float s_xs[2 * 1024]; // x i16 chunk dbuf: [64 c2=b*4+q][16 i]
  alignas(16) __shared__ float s_ps[4096];     // [4 q][16 b][64 r]; plane0 overwritten by merged
  __shared__ float s_rr[64];                   // [4 q][16 b] 1/rms

  const int t = threadIdx.x, lane = t & 63, wid = t >> 6;
  const int n0 = blockIdx.x * ITERS;

  // ---------- staging geometry (bumped per iteration) ----------
  // proj slab: wave w stages quadrant q=w>>1, rows r0=(w&1)*32+(lane>>2) and
  // r0+16. Source 16B slot XOR-swizzled by (r>>1)&3 = (lane>>3)&3 (LDS dest
  // linear as global_load_lds requires; read side uses fsl below).
  const int q0 = wid >> 1;
  const int r0 = (wid & 1) * 32 + (lane >> 2);
  const float* fq0 = (q0 == 0) ? ftl : ((q0 == 1) ? ftr : ((q0 == 2) ? fbl : fbr));
  const float* ss0 =
      fq0 + ((size_t)n0 * 64 + r0) * 256 + (((lane & 3) ^ ((lane >> 3) & 3)) << 2);
  // x chunk (waves 0-3 only, 1KB/phase): c2 = wid*16 + (lane>>2)
  const int c2 = wid * 16 + (lane >> 2);
  const float* xsrc =
      x + (((size_t)(c2 >> 2) * NN + n0) * 4 + (c2 & 3)) * 256 + (lane & 3) * 4;
  // fo quarter: linear [16r][256o]
  const float* osrc = fout + (size_t)n0 * 16384 + wid * 512 + lane * 4;

  auto ISSUE_SLAB = [&](int s) {
    float* d = s_fb + (s % 3) * 4096 + wid * 512;
    g2l16(ss0 + s * 16, d);              // rows r0
    g2l16(ss0 + 4096 + s * 16, d + 256); // rows r0+16
  };
  auto ISSUE_X = [&](int p) {
    if (wid < 4) g2l16(xsrc + p * 16, s_xs + (p & 1) * 1024 + wid * 256);
  };
  auto ISSUE_FO = [&](int h) {
    float* d = s_fb + ((16 + h) % 3) * 4096 + wid * 512;
    g2l16(osrc + h * 4096, d);
    g2l16(osrc + h * 4096 + 256, d + 256);
  };

  // compute decomposition: iseg 4i, bh b-half, rg base-r (rows rg+{0,16,32,48}), qq quadrant
  const int iseg = t & 3;
  const int bh   = (t >> 2) & 1;
  const int rg   = (t >> 3) & 15;
  const int qq   = t >> 7;
  const int fsl  = (iseg ^ ((rg >> 1) & 3)) << 2; // swizzled fv slot (floats)

#pragma unroll 1
  for (int it = 0; it < ITERS; ++it) {
    const int n = n0 + it;
    const float gn = gain[n]; // uniform -> scalar load (lgkmcnt), no vm-queue impact

    if (it == 0) { // later iters: prefetched by previous epilogue
      ISSUE_X(0);
      ISSUE_SLAB(0);
      ISSUE_SLAB(1);
    }

    float acc[4][8];
#pragma unroll
    for (int k = 0; k < 4; ++k)
#pragma unroll
      for (int b = 0; b < 8; ++b) acc[k][b] = 0.0f;

    // ---------- 16 projection phases (i16 slices) ----------
    // unroll 2 only: full unroll hoists addresses -> spill (R4 lesson).
#pragma unroll 2
    for (int p = 0; p < 16; ++p) {
      if (p < 15) ISSUE_X(p + 1);
      if (p < 14) ISSUE_SLAB(p + 2); else ISSUE_FO(p - 14);
      if (p < 15) {
        if (wid < 4) { WAITVM(5); } else { WAITVM(4); }
      } else {
        WAITVM(4);
      }
      BARRIER();

      const float* fb = s_fb + (p % 3) * 4096 + qq * 1024;
      const float* xb = s_xs + (p & 1) * 1024;
      float4 fv[4];
#pragma unroll
      for (int k = 0; k < 4; ++k)
        fv[k] = *(const float4*)(fb + (k * 16 + rg) * 16 + fsl);
#pragma unroll
      for (int h2 = 0; h2 < 2; ++h2) {
        float4 xv[4];
#pragma unroll
        for (int bb = 0; bb < 4; ++bb)
          xv[bb] = *(const float4*)(xb + ((bh * 8 + h2 * 4 + bb) * 4 + qq) * 16 + (iseg << 2));
#pragma unroll
        for (int k = 0; k < 4; ++k)
#pragma unroll
          for (int bb = 0; bb < 4; ++bb) {
            acc[k][h2 * 4 + bb] = fmaf(fv[k].x, xv[bb].x, acc[k][h2 * 4 + bb]);
            acc[k][h2 * 4 + bb] = fmaf(fv[k].y, xv[bb].y, acc[k][h2 * 4 + bb]);
            acc[k][h2 * 4 + bb] = fmaf(fv[k].z, xv[bb].z, acc[k][h2 * 4 + bb]);
            acc[k][h2 * 4 + bb] = fmaf(fv[k].w, xv[bb].w, acc[k][h2 * 4 + bb]);
          }
      }
      LGKM0();
      BARRIER(); // buffer-reuse fence
    }

    // queue now: [FO0(2), FO1(2)] (p15 left vmcnt=4)
    ISSUE_FO(2); // -> 6 outstanding

    // ---------- reduce over iseg, write P ----------
#pragma unroll
    for (int k = 0; k < 4; ++k)
#pragma unroll
      for (int b = 0; b < 8; ++b) {
        float v = acc[k][b];
        v += __shfl_xor(v, 1);
        v += __shfl_xor(v, 2);
        acc[k][b] = v;
      }
#pragma unroll
    for (int k = 0; k < 4; ++k) {
      if (iseg == k) { // static acc index
#pragma unroll
        for (int b = 0; b < 8; ++b)
          s_ps[qq * 1024 + (bh * 8 + b) * 64 + k * 16 + rg] = acc[k][b];
      }
    }
    LGKM0(); BARRIER();

    // ---------- RMS per (q,b) row ----------
#pragma unroll
    for (int j = 0; j < 8; ++j) {
      const int row = wid * 8 + j;
      const float v = s_ps[row * 64 + lane];
      float ssum = v * v;
#pragma unroll
      for (int d = 1; d < 64; d <<= 1) ssum += __shfl_xor(ssum, d);
      if (lane == 0) s_rr[row] = 1.0f / sqrtf(ssum * (1.0f / 64.0f) + 1e-6f);
    }
    LGKM0(); BARRIER();

    // ---------- merged[b][r] -> s_ps plane 0 (element-owned, race-free) ------
#pragma unroll
    for (int e0 = 0; e0 < 2; ++e0) {
      const int e = t + e0 * 512;
      const int b = e >> 6, r = e & 63;
      float m = gn;
#pragma unroll
      for (int q = 0; q < 4; ++q) m *= s_ps[q * 1024 + b * 64 + r] * s_rr[q * 16 + b];
      s_ps[b * 64 + r] = m;
    }

    // ---------- out GEMM over 4 fo quarters: thread = (2 b) x (4 o) ----------
    // need FO0 (slot1): queue [FO0 2, FO1 2, FO2 2] -> N=4
    WAITVM(4); BARRIER(); // + merged visibility
    // per-lane merged row; m(b,r) = readlane(mv_b, r) — off the LDS pipe
    const float mv0 = s_ps[(wid * 2 + 0) * 64 + lane];
    const float mv1 = s_ps[(wid * 2 + 1) * 64 + lane];

    float oa[2][4] = {{0.f, 0.f, 0.f, 0.f}, {0.f, 0.f, 0.f, 0.f}};
    auto gemq = [&](int h, const float* fsp) {
#pragma unroll
      for (int rr = 0; rr < 16; ++rr) {
        const float4 f4 = *(const float4*)(fsp + rr * 256 + (lane << 2));
        const float m0 = __uint_as_float(__builtin_amdgcn_readlane(__float_as_uint(mv0), h * 16 + rr));
        const float m1 = __uint_as_float(__builtin_amdgcn_readlane(__float_as_uint(mv1), h * 16 + rr));
        oa[0][0] = fmaf(m0, f4.x, oa[0][0]); oa[0][1] = fmaf(m0, f4.y, oa[0][1]);
        oa[0][2] = fmaf(m0, f4.z, oa[0][2]); oa[0][3] = fmaf(m0, f4.w, oa[0][3]);
        oa[1][0] = fmaf(m1, f4.x, oa[1][0]); oa[1][1] = fmaf(m1, f4.y, oa[1][1]);
        oa[1][2] = fmaf(m1, f4.z, oa[1][2]); oa[1][3] = fmaf(m1, f4.w, oa[1][3]);
      }
    };

    gemq(0, s_fb + 1 * 4096);            // FO0
    BARRIER();                           // slot1 readers done
    ISSUE_FO(3);                         // FO3 -> slot1; queue [FO1 2, FO2 2, FO3 2]
    // need FO1 (slot2): N=4
    WAITVM(4); BARRIER();
    gemq(1, s_fb + 2 * 4096);            // FO1
    // need FO2 (slot0): N=2
    WAITVM(2); BARRIER();
    gemq(2, s_fb + 0 * 4096);            // FO2
    // need FO3 (slot1): once-per-n drain
    WAITVM(0); BARRIER();                // all waves also past gemq(2) -> slot0 free
    if (it != ITERS - 1) {
      // start next n's prologue NOW: slot0 + x buf0 free; slot1 still being
      // read by gemq(3) below -> its slab goes after the next barrier.
      ss0 += 16384; xsrc += 1024; osrc += 16384;
      ISSUE_X(0);
      ISSUE_SLAB(0);
    }
    gemq(3, s_fb + 1 * 4096);            // FO3
    BARRIER();                           // slot1 readers done
    if (it != ITERS - 1) ISSUE_SLAB(1);  // -> slot1
    // queue now (non-last): [X0'(w<4), S0'(2), S1'(2)] — the prologue pattern.

    // ---------- residual: tail re-read of x (R5 position; spill-free) -------
#pragma unroll
    for (int bb = 0; bb < 2; ++bb) {
      const int b = wid * 2 + bb;
      const float* xe = x + (((size_t)b * NN + n) * 4) * 256 + (lane << 2);
      float4 x0 = *(const float4*)(xe);
      float4 x1 = *(const float4*)(xe + 256);
      float4 x2 = *(const float4*)(xe + 512);
      float4 x3 = *(const float4*)(xe + 768);
      float4 o4;
      o4.x = oa[bb][0] + 0.25f * (x0.x + x1.x + x2.x + x3.x);
      o4.y = oa[bb][1] + 0.25f * (x0.y + x1.y + x2.y + x3.y);
      o4.z = oa[bb][2] + 0.25f * (x0.z + x1.z + x2.z + x3.z);
      o4.w = oa[bb][3] + 0.25f * (x0.w + x1.w + x2.w + x3.w);
      *(float4*)(out + ((size_t)b * NN + n) * 256 + (lane << 2)) = o4;
    }
  }
}

extern "C" void kernel_launch(void* const* d_in, const int* in_sizes, int n_in,
                              void* d_out, int out_size, void* d_ws, size_t ws_size,
                              hipStream_t stream) {
  const float* x   = (const float*)d_in[0];
  const float* ftl = (const float*)d_in[1];
  const float* ftr = (const float*)d_in[2];
  const float* fbl = (const float*)d_in[3];
  const float* fbr = (const float*)d_in[4];
  const float* fo  = (const float*)d_in[5];
  const float* gn  = (const float*)d_in[6];
  float* o = (float*)d_out;
  cpquad_kernel<<<dim3(NN / ITERS), dim3(512), 0, stream>>>(x, ftl, ftr, fbl, fbr, fo, gn, o);
}

// Round 8
// 245.883 us; speedup vs baseline: 1.5094x; 1.4232x over previous
//
#include <hip/hip_runtime.h>
#include <math.h>

// CPQuadRankLayer: B=16, N=2048, IN=OUT=256, R=64, Q=4.
// out[b,n,o] = sum_r ( prod_q rmsnorm_r(x[b,n,q,:] @ Fq[n]^T) )[r] * gain[n] * Fo[n,r,o]
//              + mean_q x[b,n,q,o]
//
// R8 = R5 skeleton (non-persistent, 1 WG per n, 512 thr; persistent variants
// R6/R7 both lost to register spill) at HALF granularity for 3 WG/CU:
//   i8 slices -> 32 phases; slab ring 3 x 8KB; x chunks 2 x 2KB; fo streamed
//   as 8 x 8KB eighths. LDS = 44.25KB -> 3 WGs/CU (24 waves, 75% occ).
//   __launch_bounds__(512,3) -> ~85-reg cap (empirical cap = 256/arg2).
// In-loop live set by construction ~65 regs: fv 4xfloat2, xv 2 rows at a
// time, acc[4][8]. b64 LDS reads are 2-deep (free) -> swizzle dropped.
// Counted vmcnt per wave class (never 0 mid-stream), raw s_barrier.

#define WAITVM(NLIT) asm volatile("s_waitcnt vmcnt(" #NLIT ") lgkmcnt(0)" ::: "memory")
#define LGKM0()      asm volatile("s_waitcnt lgkmcnt(0)" ::: "memory")
#define BARRIER()    __builtin_amdgcn_s_barrier()

__device__ __forceinline__ void g2l16(const float* g, float* l) {
  __builtin_amdgcn_global_load_lds(
      (const __attribute__((address_space(1))) void*)g,
      (__attribute__((address_space(3))) void*)l, 16, 0, 0);
}

#define NN 2048

__global__ __launch_bounds__(512, 3) void cpquad_kernel(
    const float* __restrict__ x,
    const float* __restrict__ ftl, const float* __restrict__ ftr,
    const float* __restrict__ fbl, const float* __restrict__ fbr,
    const float* __restrict__ fout, const float* __restrict__ gain,
    float* __restrict__ out) {

  // LDS: 6144 + 1024 + 4096 + 64 floats = 44.25 KB -> 3 WG/CU
  alignas(16) __shared__ float s_fb[3 * 2048]; // ring: proj slab [4q][64r][8i] / fo eighth [8r][256o]
  alignas(16) __shared__ float s_xs[2 * 512];  // x i8 chunk dbuf: [64 c2=b*4+q][8 i]
  alignas(16) __shared__ float s_ps[4096];     // [4 q][16 b][64 r]; plane0 overwritten by merged
  __shared__ float s_rr[64];                   // [4 q][16 b] 1/rms

  const int t = threadIdx.x, lane = t & 63, wid = t >> 6;
  const int n = blockIdx.x;
  const float gn = gain[n]; // uniform -> scalar load (lgkm queue, not vmcnt)

  // ---------- staging sources ----------
  // slab: 8KB = 8 wave-chunks of 1KB. Wave w: quadrant q=w>>1, rows
  // r = (w&1)*32 + (lane>>1), 16B half h=lane&1 of the 32B row-slice.
  const int q0 = wid >> 1;
  const int r0 = (wid & 1) * 32 + (lane >> 1);
  const float* fq0 = (q0 == 0) ? ftl : ((q0 == 1) ? ftr : ((q0 == 2) ? fbl : fbr));
  const float* ss0 = fq0 + ((size_t)n * 64 + r0) * 256 + (lane & 1) * 4;
  // x chunk (2KB, waves 0-1): c2 = wid*32 + (lane>>1), b=c2>>2, q=c2&3
  const int c2 = wid * 32 + (lane >> 1);
  const float* xsrc =
      x + (((size_t)(c2 >> 2) * NN + n) * 4 + (c2 & 3)) * 256 + (lane & 1) * 4;
  // fo eighth [8r][256o] = 8KB; wave w stages row w: 1KB linear
  const float* osrc = fout + (size_t)n * 16384 + wid * 256 + lane * 4;

  // ---------- issue helpers (wave-uniform LDS base; HW scatters lane*16B) ---
  auto ISSUE_SLAB = [&](int s) {
    g2l16(ss0 + s * 8, s_fb + (s % 3) * 2048 + wid * 256);
  };
  auto ISSUE_X = [&](int p) {
    if (wid < 2) g2l16(xsrc + p * 8, s_xs + (p & 1) * 512 + wid * 256);
  };
  auto ISSUE_E = [&](int h) {
    g2l16(osrc + h * 2048, s_fb + ((32 + h) % 3) * 2048 + wid * 256);
  };

  // ---------- prologue ----------
  ISSUE_X(0);
  ISSUE_SLAB(0);
  ISSUE_SLAB(1);

  // compute decomposition: t = qq(2b) | rg(4b) | bh(1b) | iseg(2b)
  const int iseg = t & 3;         // 2-float i-slot within the 8-float slice
  const int bh   = (t >> 2) & 1;  // b half
  const int rg   = (t >> 3) & 15; // rows rg + {0,16,32,48}
  const int qq   = t >> 7;        // quadrant

  float acc[4][8];
#pragma unroll
  for (int k = 0; k < 4; ++k)
#pragma unroll
    for (int b = 0; b < 8; ++b) acc[k][b] = 0.0f;

  // ---------- 32 projection phases (i8 slices) ----------
  // unroll 2 only: full unroll hoists addresses -> spill (R4 lesson).
#pragma unroll 2
  for (int p = 0; p < 32; ++p) {
    if (p < 31) ISSUE_X(p + 1);
    if (p < 30) ISSUE_SLAB(p + 2); else ISSUE_E(p - 30);
    // per-wave queues: wid<2 steady [S(p),X(p),S(p+1)] + issue {X(p+1),S(p+2)}
    //   -> WAITVM(3); wid>=2 [S(p),S(p+1)] + issue -> WAITVM(2).
    // p=31 (no X issue): both classes end at [E0,E1] via WAITVM(2).
    if (p < 31) {
      if (wid < 2) { WAITVM(3); } else { WAITVM(2); }
    } else {
      WAITVM(2);
    }
    BARRIER();

    const float* fb = s_fb + (p % 3) * 2048 + qq * 512;
    const float* xb = s_xs + (p & 1) * 512;
    float2 fv[4];
#pragma unroll
    for (int k = 0; k < 4; ++k)
      fv[k] = *(const float2*)(fb + (k * 16 + rg) * 8 + iseg * 2);
    // xv two rows at a time: live window fv(8) + xv(4) + acc(32)
#pragma unroll
    for (int h2 = 0; h2 < 4; ++h2) {
      const float2 xv0 = *(const float2*)(xb + ((bh * 8 + h2 * 2 + 0) * 4 + qq) * 8 + iseg * 2);
      const float2 xv1 = *(const float2*)(xb + ((bh * 8 + h2 * 2 + 1) * 4 + qq) * 8 + iseg * 2);
#pragma unroll
      for (int k = 0; k < 4; ++k) {
        acc[k][h2 * 2 + 0] = fmaf(fv[k].x, xv0.x, acc[k][h2 * 2 + 0]);
        acc[k][h2 * 2 + 0] = fmaf(fv[k].y, xv0.y, acc[k][h2 * 2 + 0]);
        acc[k][h2 * 2 + 1] = fmaf(fv[k].x, xv1.x, acc[k][h2 * 2 + 1]);
        acc[k][h2 * 2 + 1] = fmaf(fv[k].y, xv1.y, acc[k][h2 * 2 + 1]);
      }
    }
    LGKM0();
    BARRIER(); // buffer-reuse fence
  }

  // queue now: [E0, E1] for all waves
  ISSUE_E(2); // -> 3 outstanding

  // ---------- reduce over iseg, write P ----------
#pragma unroll
  for (int k = 0; k < 4; ++k)
#pragma unroll
    for (int b = 0; b < 8; ++b) {
      float v = acc[k][b];
      v += __shfl_xor(v, 1);
      v += __shfl_xor(v, 2);
      acc[k][b] = v;
    }
#pragma unroll
  for (int k = 0; k < 4; ++k) {
    if (iseg == k) { // static acc index
#pragma unroll
      for (int b = 0; b < 8; ++b)
        s_ps[qq * 1024 + (bh * 8 + b) * 64 + k * 16 + rg] = acc[k][b];
    }
  }
  LGKM0(); BARRIER();

  // ---------- RMS per (q,b) row ----------
#pragma unroll
  for (int j = 0; j < 8; ++j) {
    const int row = wid * 8 + j;
    const float v = s_ps[row * 64 + lane];
    float ssum = v * v;
#pragma unroll
    for (int d = 1; d < 64; d <<= 1) ssum += __shfl_xor(ssum, d);
    if (lane == 0) s_rr[row] = 1.0f / sqrtf(ssum * (1.0f / 64.0f) + 1e-6f);
  }
  LGKM0(); BARRIER();

  // ---------- merged[b][r] -> s_ps plane 0 (element-owned, race-free) -------
#pragma unroll
  for (int e0 = 0; e0 < 2; ++e0) {
    const int e = t + e0 * 512;
    const int b = e >> 6, r = e & 63;
    float m = gn;
#pragma unroll
    for (int q = 0; q < 4; ++q) m *= s_ps[q * 1024 + b * 64 + r] * s_rr[q * 16 + b];
    s_ps[b * 64 + r] = m;
  }

  // ---------- out GEMM over 8 fo eighths: thread = (2 b) x (4 o) ------------
  float oa[2][4] = {{0.f, 0.f, 0.f, 0.f}, {0.f, 0.f, 0.f, 0.f}};
  float mv0, mv1;

#pragma unroll
  for (int h = 0; h < 8; ++h) {
    // queue before wait: [E(h), E(h+1), E(h+2)] (capped at E7)
    if (h <= 5)      { WAITVM(2); }
    else if (h == 6) { WAITVM(1); }
    else             { WAITVM(0); }
    BARRIER(); // E(h) visible to all + (h==0) merged visible
    if (h == 0) {
      mv0 = s_ps[(wid * 2 + 0) * 64 + lane];
      mv1 = s_ps[(wid * 2 + 1) * 64 + lane];
    }
    const float* fsp = s_fb + ((2 + h) % 3) * 2048;
#pragma unroll
    for (int rr = 0; rr < 8; ++rr) {
      const float4 f4 = *(const float4*)(fsp + rr * 256 + (lane << 2));
      const float m0 = __uint_as_float(__builtin_amdgcn_readlane(__float_as_uint(mv0), h * 8 + rr));
      const float m1 = __uint_as_float(__builtin_amdgcn_readlane(__float_as_uint(mv1), h * 8 + rr));
      oa[0][0] = fmaf(m0, f4.x, oa[0][0]); oa[0][1] = fmaf(m0, f4.y, oa[0][1]);
      oa[0][2] = fmaf(m0, f4.z, oa[0][2]); oa[0][3] = fmaf(m0, f4.w, oa[0][3]);
      oa[1][0] = fmaf(m1, f4.x, oa[1][0]); oa[1][1] = fmaf(m1, f4.y, oa[1][1]);
      oa[1][2] = fmaf(m1, f4.z, oa[1][2]); oa[1][3] = fmaf(m1, f4.w, oa[1][3]);
    }
    LGKM0();
    BARRIER(); // slot readers done -> safe to re-DMA
    if (h <= 4) ISSUE_E(h + 3);
  }

  // ---------- residual: tail re-read of x (all vmcnt drained at h=7) --------
#pragma unroll
  for (int bb = 0; bb < 2; ++bb) {
    const int b = wid * 2 + bb;
    const float* xe = x + (((size_t)b * NN + n) * 4) * 256 + (lane << 2);
    float4 x0 = *(const float4*)(xe);
    float4 x1 = *(const float4*)(xe + 256);
    float4 x2 = *(const float4*)(xe + 512);
    float4 x3 = *(const float4*)(xe + 768);
    float4 o4;
    o4.x = oa[bb][0] + 0.25f * (x0.x + x1.x + x2.x + x3.x);
    o4.y = oa[bb][1] + 0.25f * (x0.y + x1.y + x2.y + x3.y);
    o4.z = oa[bb][2] + 0.25f * (x0.z + x1.z + x2.z + x3.z);
    o4.w = oa[bb][3] + 0.25f * (x0.w + x1.w + x2.w + x3.w);
    *(float4*)(out + ((size_t)b * NN + n) * 256 + (lane << 2)) = o4;
  }
}

extern "C" void kernel_launch(void* const* d_in, const int* in_sizes, int n_in,
                              void* d_out, int out_size, void* d_ws, size_t ws_size,
                              hipStream_t stream) {
  const float* x   = (const float*)d_in[0];
  const float* ftl = (const float*)d_in[1];
  const float* ftr = (const float*)d_in[2];
  const float* fbl = (const float*)d_in[3];
  const float* fbr = (const float*)d_in[4];
  const float* fo  = (const float*)d_in[5];
  const float* gn  = (const float*)d_in[6];
  float* o = (float*)d_out;
  cpquad_kernel<<<dim3(NN), dim3(512), 0, stream>>>(x, ftl, ftr, fbl, fbr, fo, gn, o);
}